// Round 13
// baseline (76.698 us; speedup 1.0000x reference)
//
#include <hip/hip_runtime.h>
#include <hip/hip_bf16.h>
#include <stdint.h>

#define B_ 2
#define N_ 3000
#define F_ 64
#define H_ 4
#define D_ 32
#define K_ 128          // H_*D_ output feature cols
#define KT_ 9           // 9 k-tiles of 16 -> 144 cols (128 feat + 4 denom + 12 pad)
#define NCHP_ 96        // padded m-chunks (3072 m; 94 real + 2 zero)
#define NROWT_ 188      // ceil(3000/16) 16-row tiles per batch
#define NRG_ 47         // 64-row groups per batch
#define S_ 8            // split-K factor: each split = exactly 12 chunks (384 cols)
#define CHB_ 9216       // bytes per G chunk (9 tiles x 64 lanes x 16B)
#define PTB_ 9216       // floats per partial block (4 waves x 9 tiles x 4 x 64)

typedef short bf16x8 __attribute__((ext_vector_type(8)));
typedef float f32x4  __attribute__((ext_vector_type(4)));

__device__ __forceinline__ unsigned short f2bf(float f) {
    uint32_t x = __float_as_uint(f);
    return (unsigned short)((x + 0x7FFFu + ((x >> 16) & 1u)) >> 16);  // RNE
}

// ---- Pass 1: feat[b][h][n][d] = h . kernel ; e2[b][h][n] = feat . att_k2 ; node_mask
__global__ void k_feat(const float* __restrict__ hin, const float* __restrict__ kern,
                       const float* __restrict__ ak2,
                       float* __restrict__ feat, float* __restrict__ e2,
                       float* __restrict__ nmask) {
    int b = blockIdx.x / N_;
    int n = blockIdx.x % N_;
    __shared__ float hrow[F_];
    int tid = threadIdx.x;                       // 128 threads: (h = tid>>5, d = tid&31)
    if (tid < F_) hrow[tid] = hin[(size_t)(b * N_ + n) * F_ + tid];
    __syncthreads();
    int hh = tid >> 5, d = tid & 31;
    float acc = 0.f;
    #pragma unroll
    for (int f = 0; f < F_; ++f)
        acc = fmaf(hrow[f], kern[(hh * F_ + f) * D_ + d], acc);
    feat[((size_t)(b * H_ + hh) * N_ + n) * D_ + d] = acc;
    float v = acc * ak2[hh * D_ + d];
    #pragma unroll
    for (int o = 16; o >= 1; o >>= 1) v += __shfl_xor(v, o, 32);
    if (d == 0) e2[(size_t)(b * H_ + hh) * N_ + n] = v;
    unsigned long long bal = __ballot(tid < F_ && hrow[tid & (F_ - 1)] != 0.0f);
    if (tid == 0) nmask[b * N_ + n] = (bal != 0ull) ? 1.0f : 0.0f;
}

// ---- Pass 2: G in MFMA-B-fragment order: G[((b*96+ch)*9+t)*64 + lane] = ushort8
//      lane: rg=lane>>4, col=lane&15 ; element j -> Gmat[m = ch*32+rg*8+j][k = t*16+col]
//      Gmat[m][k<128] = w[h][m]*feat[h][m][d] (h=k>>5,d=k&31); k in 128..131 -> w[k-128][m]; else 0
//      w[h][m] = exp(e2[h][m])  (max cancels in the num/den ratio; |e2|~O(1), no overflow)
__global__ void k_G(const float* __restrict__ feat, const float* __restrict__ e2,
                    bf16x8* __restrict__ G) {
    int idx = blockIdx.x * blockDim.x + threadIdx.x;
    const int total = B_ * NCHP_ * KT_ * 64;
    if (idx >= total) return;
    int lane = idx & 63;
    int t  = (idx >> 6) % KT_;
    int ch = ((idx >> 6) / KT_) % NCHP_;
    int b  = idx / (64 * KT_ * NCHP_);
    int rg = lane >> 4, col = lane & 15;
    int k  = t * 16 + col;
    int m0 = ch * 32 + rg * 8;
    float vals[8];
    if (k < K_ + H_) {
        int hh, d; bool wonly;
        if (k < K_) { hh = k >> 5; d = k & 31; wonly = false; }
        else        { hh = k - K_; d = 0;      wonly = true;  }
        const float* e2p = e2 + (size_t)(b * H_ + hh) * N_;
        const float* fp  = feat + (size_t)(b * H_ + hh) * N_ * D_ + d;
        #pragma unroll
        for (int j = 0; j < 8; ++j) {
            int m = m0 + j;
            float v = 0.f;
            if (m < N_) {
                float w = __expf(e2p[m]);
                v = wonly ? w : w * fp[(size_t)m * D_];
            }
            vals[j] = v;
        }
    } else {
        #pragma unroll
        for (int j = 0; j < 8; ++j) vals[j] = 0.f;
    }
    union { bf16x8 v; unsigned short u[8]; } o;
    #pragma unroll
    for (int j = 0; j < 8; ++j) o.u[j] = f2bf(vals[j]);
    G[idx] = o.v;
}

// ---- Pass 3 helper: async global->LDS, 16B per lane (dst = uniform base + lane*16)
__device__ __forceinline__ void g2lds16(const void* g, void* l) {
    __builtin_amdgcn_global_load_lds(
        (const __attribute__((address_space(1))) void*)g,
        (__attribute__((address_space(3))) void*)l, 16, 0, 0);
}

// 4 waves stage one 9216B G chunk: w0{0,1} w1{2,3} w2{4,5} w3{6,7,8}
__device__ __forceinline__ void stage_chunk(const char* src_ln, char* dst, int w) {
    int t0 = 2 * w * 1024;
    g2lds16(src_ln + t0,        dst + t0);
    g2lds16(src_ln + t0 + 1024, dst + t0 + 1024);
    if (w == 3) g2lds16(src_ln + 8192, dst + 8192);
}

// ---- Pass 3: FUSED bit-pack + split-K GEMM. Grid = B x NRG x S (752 blocks, 4 waves).
//      Phase A: block streams its 64-row x 384-col adjacency slab coalesced,
//      ballot-packs to bitw[64][13] in LDS (72 MB total across grid, read ONCE).
//      Phase B: 12-chunk MFMA loop; G staged cooperatively via global_load_lds with
//      per-wave COUNTED vmcnt + raw s_barrier (no vmcnt(0) gang-drain). Wave w owns
//      rows rg64*64+w*16..+15, all 9 k-tiles. Partial (4x9x4x64 f32) -> ws.
__global__ void __launch_bounds__(256, 2) k_main(
        const float* __restrict__ a, const bf16x8* __restrict__ G,
        float* __restrict__ partial) {
    __shared__ __align__(16) bf16x8 Gbuf[2][KT_ * 64];   // 18,432 B
    __shared__ uint32_t bitw[64][13];                    // 3,328 B (pad 13: no bank conflict)
    int bid = blockIdx.x;
    int s    = bid % S_;
    int rg64 = (bid / S_) % NRG_;
    int b    = bid / (S_ * NRG_);
    int w = threadIdx.x >> 6;                     // wave 0..3
    int l = threadIdx.x & 63;
    int rg = l >> 4, col = l & 15;

    // ---- Phase A: pack adjacency slab (rows rg64*64+0..63, cols s*384+0..383)
    for (int r = 0; r < 16; ++r) {
        int rl = w * 16 + r;
        int rowa = min(rg64 * 64 + rl, N_ - 1);
        const float* arow = a + (size_t)(b * N_ + rowa) * N_;
        #pragma unroll
        for (int sl = 0; sl < 6; ++sl) {
            int m = s * 384 + sl * 64 + l;
            float v = (m < N_) ? arow[m] : 0.f;
            unsigned long long bal = __ballot(v != 0.f);
            if (l == 0)  bitw[rl][sl * 2]     = (uint32_t)bal;
            if (l == 32) bitw[rl][sl * 2 + 1] = (uint32_t)(bal >> 32);
        }
    }
    __syncthreads();                              // bits published (full drain, once)

    // ---- Phase B: 12-chunk MFMA loop, counted-vmcnt double-buffered G staging
    const char* Gsrc = (const char*)G + (size_t)(b * NCHP_ + s * 12) * CHB_ + (size_t)l * 16;
    char* buf0 = (char*)&Gbuf[0][0];
    char* buf1 = (char*)&Gbuf[1][0];

    f32x4 acc[KT_];
    #pragma unroll
    for (int t = 0; t < KT_; ++t) acc[t] = (f32x4){0.f, 0.f, 0.f, 0.f};

    stage_chunk(Gsrc, buf0, w);                   // prologue: chunk 0 -> buf0
    #pragma unroll
    for (int i = 0; i < 12; ++i) {
        char* cur = (i & 1) ? buf1 : buf0;
        char* nxt = (i & 1) ? buf0 : buf1;
        if (i + 1 < 12) {
            stage_chunk(Gsrc + (size_t)(i + 1) * CHB_, nxt, w);
            // own stage(i) retired; stage(i+1) stays in flight
            if (w == 3) asm volatile("s_waitcnt vmcnt(3)" ::: "memory");
            else        asm volatile("s_waitcnt vmcnt(2)" ::: "memory");
        } else {
            asm volatile("s_waitcnt vmcnt(0)" ::: "memory");
        }
        __builtin_amdgcn_sched_barrier(0);
        __builtin_amdgcn_s_barrier();             // all waves' chunk-i data in LDS
        __builtin_amdgcn_sched_barrier(0);

        uint32_t word = bitw[w * 16 + col][i];
        uint32_t mb = (word >> (rg * 8)) & 0xFFu;
        union { uint32_t u[4]; bf16x8 v; } af;    // bf16 1.0 = 0x3F80, exact 0/1
        af.u[0] = ((mb & 1u)   ? 0x3F80u : 0u) | ((mb & 2u)   ? 0x3F800000u : 0u);
        af.u[1] = ((mb & 4u)   ? 0x3F80u : 0u) | ((mb & 8u)   ? 0x3F800000u : 0u);
        af.u[2] = ((mb & 16u)  ? 0x3F80u : 0u) | ((mb & 32u)  ? 0x3F800000u : 0u);
        af.u[3] = ((mb & 64u)  ? 0x3F80u : 0u) | ((mb & 128u) ? 0x3F800000u : 0u);
        #pragma unroll
        for (int t = 0; t < KT_; ++t) {
            bf16x8 g = *(const bf16x8*)(cur + t * 1024 + l * 16);   // ds_read_b128
            acc[t] = __builtin_amdgcn_mfma_f32_16x16x32_bf16(af.v, g, acc[t], 0, 0, 0);
        }
        __builtin_amdgcn_sched_barrier(0);
        __builtin_amdgcn_s_barrier();             // all reads of buf[i&1] done -> safe overwrite
    }

    // partial write: wave-owned rows, coalesced 64-lane stores
    float* pw = partial + (size_t)bid * PTB_ + w * (KT_ * 256);
    #pragma unroll
    for (int t = 0; t < KT_; ++t)
        #pragma unroll
        for (int r = 0; r < 4; ++r)
            pw[t * 256 + r * 64 + l] = acc[t][r];
}

// ---- Pass 4: sum 8 partials per 16-row tile + fused epilogue (divide/bias/relu/mask)
__global__ void __launch_bounds__(256) k_red(
        const float* __restrict__ partial, const float* __restrict__ bias,
        const float* __restrict__ nmask, float* __restrict__ out) {
    int rt = blockIdx.x % NROWT_;                 // 16-row tile 0..187
    int b  = blockIdx.x / NROWT_;
    int nbase = rt * 16;
    int rg64  = rt >> 2;                          // 64-row group
    int wslot = rt & 3;                           // wave slot within k_main block
    int tid = threadIdx.x;
    __shared__ float sm[KT_ * 256];
    const float* pbase = partial + (size_t)((b * NRG_ + rg64) * S_) * PTB_ + wslot * (KT_ * 256);
    #pragma unroll
    for (int k = 0; k < 9; ++k) {
        int flat = tid + k * 256;
        float s = 0.f;
        #pragma unroll
        for (int sp = 0; sp < S_; ++sp) s += pbase[(size_t)sp * PTB_ + flat];
        sm[flat] = s;
    }
    __syncthreads();
    #pragma unroll
    for (int k = 0; k < 9; ++k) {
        int flat = tid + k * 256;
        if (flat < 2048) {                        // tiles 0..7 are outputs
            int t4r = flat >> 6;                  // t*4+r
            int t = t4r >> 2, r = t4r & 3;
            int lane = flat & 63;
            int rg = lane >> 4, col = lane & 15;
            int rowi = rg * 4 + r;
            int n = nbase + rowi;
            if (n < N_) {
                int hh = t >> 1;
                int r2 = rowi & 3, rg2 = rowi >> 2;
                float den = sm[(32 + r2) * 64 + (rg2 << 4) + hh];
                float v = (den > 0.f) ? sm[flat] / den : 0.f;
                v += bias[t * 16 + col];
                v = fmaxf(v, 0.f);
                v *= nmask[b * N_ + n];
                out[(size_t)(b * N_ + n) * K_ + t * 16 + col] = v;
            }
        }
    }
}

extern "C" void kernel_launch(void* const* d_in, const int* in_sizes, int n_in,
                              void* d_out, int out_size, void* d_ws, size_t ws_size,
                              hipStream_t stream) {
    const float* h    = (const float*)d_in[0];
    const float* a    = (const float*)d_in[1];
    const float* kern = (const float*)d_in[2];
    // d_in[3] = att_k1: cancels in row-softmax, unused
    const float* ak2  = (const float*)d_in[4];
    const float* bias = (const float*)d_in[5];
    float* out = (float*)d_out;

    char* ws = (char*)d_ws;
    size_t o_feat  = 0;                                   // 3,072,000 B
    size_t o_e2    = o_feat  + 3072000;                   //    96,000 B
    size_t o_nmask = o_e2    + 96000;                     //    24,064 B (pad)
    size_t o_G     = o_nmask + 24064;                     // 2*96*9216 = 1,769,472 B
    size_t o_part  = o_G     + 1769472;                   // 752*9216*4 = 27,721,728 B
    float*  feat  = (float*)(ws + o_feat);
    float*  e2    = (float*)(ws + o_e2);
    float*  nmask = (float*)(ws + o_nmask);
    bf16x8* G     = (bf16x8*)(ws + o_G);
    float*  part  = (float*)(ws + o_part);

    k_feat<<<dim3(B_ * N_), dim3(128), 0, stream>>>(h, kern, ak2, feat, e2, nmask);
    int gtot = B_ * NCHP_ * KT_ * 64;
    k_G   <<<dim3((gtot + 255) / 256), dim3(256), 0, stream>>>(feat, e2, G);
    k_main<<<dim3(B_ * NRG_ * S_), dim3(256), 0, stream>>>(a, G, part);
    k_red <<<dim3(B_ * NROWT_), dim3(256), 0, stream>>>(part, bias, nmask, out);
}